// Round 19
// baseline (3060.224 us; speedup 1.0000x reference)
//
#include <hip/hip_runtime.h>
#include <stdint.h>

typedef __attribute__((ext_vector_type(8))) short bf16x8;
typedef __attribute__((ext_vector_type(4))) float f32x4;
typedef unsigned short u16;
typedef unsigned int u32;

#define MTOK 2048
#define DMODEL 1024
#define NCELL 4096
#define DCELL 256
#define DFF 4096
#define NVOCAB 50257
#define VPAD_LD 50304          // 393 * 128, aligned pad leading dim
#define NCONV8 (NVOCAB * 128)  // embed 8-elem groups

static __device__ __forceinline__ u16 f2bf(float f) {
  u32 u = __builtin_bit_cast(u32, f);
  u = (u + 0x7FFFu + ((u >> 16) & 1u)) >> 16;
  return (u16)u;
}
static __device__ __forceinline__ u32 pk2(float a, float b) {
  return (u32)f2bf(a) | ((u32)f2bf(b) << 16);
}
static __device__ __forceinline__ float sigm(float x) { return 1.0f / (1.0f + __expf(-x)); }

// async global->LDS, 16 B per lane; lds dest = wave-uniform base + lane*16
static __device__ __forceinline__ void glds16(const void* g, void* l) {
  __builtin_amdgcn_global_load_lds(
      (const __attribute__((address_space(1))) void*)g,
      (__attribute__((address_space(3))) void*)l, 16, 0, 0);
}

static __device__ __forceinline__ float blockReduceSum(float v) {
#pragma unroll
  for (int o = 32; o > 0; o >>= 1) v += __shfl_xor(v, o);
  __shared__ float sm[4];
  __syncthreads();
  if ((threadIdx.x & 63) == 0) sm[threadIdx.x >> 6] = v;
  __syncthreads();
  return sm[0] + sm[1] + sm[2] + sm[3];
}

// 1024-thread block reduce of a PAIR (16 waves)
static __device__ __forceinline__ void blockReducePair1024(
    float& a, float& b, float* sm)
{
#pragma unroll
  for (int o = 32; o > 0; o >>= 1) { a += __shfl_xor(a, o); b += __shfl_xor(b, o); }
  int wv = threadIdx.x >> 6;
  if ((threadIdx.x & 63) == 0) { sm[wv * 2] = a; sm[wv * 2 + 1] = b; }
  __syncthreads();
  float ra = 0.f, rb = 0.f;
#pragma unroll
  for (int i = 0; i < 16; ++i) { ra += sm[i * 2]; rb += sm[i * 2 + 1]; }
  __syncthreads();
  a = ra; b = rb;
}

// embed fp32 -> bf16, one 8-elem group per thread
static __device__ __forceinline__ void conv_group(
    int i, const float* emb, u16* emb_bf)
{
  const float4* s = (const float4*)(emb + (size_t)i * 8);
  float4 a = s[0], b = s[1];
  *(uint4*)(emb_bf + (size_t)i * 8) =
      make_uint4(pk2(a.x, a.y), pk2(a.z, a.w), pk2(b.x, b.y), pk2(b.z, b.w));
}

// ---------------------------------------------------------------------------
// m97-style GEMM device body: C[2048,N] = A[2048,K](bf16) x B[N,K]^T(bf16)
// EPI 0: Cf = alpha*acc          EPI 1: residual r=Res+acc -> Cf,f2bf->Cb
// EPI 2: predicated col<NB       EPI 3: fused SwiGLU -> bf16 Cb
// EPI 4: nontemporal aligned f32 store (full-lane coverage; vpad)
// ---------------------------------------------------------------------------
template<int TM, int TN, int EPI>
static __device__ __forceinline__ void v3_body(
    int bid, int T, char* smem,
    const u16* A, const u16* B,
    float* Cf, u16* Cb, const float* Res,
    int NB, int K, int ldc, float alpha)
{
  u16* As = (u16*)smem;
  u16* Bs = (u16*)(smem + TM * 128);
  constexpr int MI = TM / 32;
  constexpr int NI = TN / 32;
  constexpr int ACH = TM / 32;
  constexpr int BCH = TN / 32;
  constexpr int MB = 2048 / TM;
  const int tid = threadIdx.x;
  const int w = (bid & 7) * (T >> 3) + (bid >> 3);
  const int m0 = (w % MB) * TM;
  const int n0 = (w / MB) * TN;
  const int l = tid & 63;
  const int wv = tid >> 6;
  const int wm = wv >> 1, wn = wv & 1;
  const int lr = l & 15, lg = l >> 4;
  const int wbase = tid & ~63;

  f32x4 acc[MI][NI] = {};

  const int row_ = tid >> 3;
  const int kc_ = (tid & 7) << 3;
  const int nk = K >> 6;

  for (int s = 0; s < nk; ++s) {
    const int k0 = s << 6;
#pragma unroll
    for (int c = 0; c < ACH; ++c) {
      int row = c * 32 + row_;
      glds16(&A[(size_t)(m0 + row) * K + k0 + kc_],
             &As[(size_t)(c * 256 + wbase) * 8]);
    }
#pragma unroll
    for (int c = 0; c < BCH; ++c) {
      int row = c * 32 + row_;
      int gr = n0 + row; if (gr > NB - 1) gr = NB - 1;
      glds16(&B[(size_t)gr * K + k0 + kc_],
             &Bs[(size_t)(c * 256 + wbase) * 8]);
    }
    __syncthreads();
#pragma unroll
    for (int kk = 0; kk < 2; ++kk) {
      bf16x8 fa[MI], fb[NI];
#pragma unroll
      for (int mi = 0; mi < MI; ++mi)
        fa[mi] = *(const bf16x8*)&As[(wm * (TM / 2) + mi * 16 + lr) * 64 + kk * 32 + lg * 8];
#pragma unroll
      for (int ni = 0; ni < NI; ++ni)
        fb[ni] = *(const bf16x8*)&Bs[(wn * (TN / 2) + ni * 16 + lr) * 64 + kk * 32 + lg * 8];
#pragma unroll
      for (int mi = 0; mi < MI; ++mi)
#pragma unroll
        for (int ni = 0; ni < NI; ++ni)
          acc[mi][ni] = __builtin_amdgcn_mfma_f32_16x16x32_bf16(fa[mi], fb[ni], acc[mi][ni], 0, 0, 0);
    }
    __syncthreads();
  }

#pragma unroll
  for (int mi = 0; mi < MI; ++mi)
#pragma unroll
    for (int ni = 0; ni < NI; ++ni) {
      int col = n0 + wn * (TN / 2) + ni * 16 + lr;
#pragma unroll
      for (int j = 0; j < 4; ++j) {
        int row = m0 + wm * (TM / 2) + mi * 16 + lg * 4 + j;
        float v = acc[mi][ni][j];
        if constexpr (EPI == 0) {
          Cf[(size_t)row * ldc + col] = v * alpha;
        } else if constexpr (EPI == 1) {
          size_t off = (size_t)row * ldc + col;
          float r = Res[off] + v;
          Cf[off] = r;
          Cb[off] = f2bf(r);
        } else if constexpr (EPI == 2) {
          if (col < NB) Cf[(size_t)row * ldc + col] = v;
        } else if constexpr (EPI == 3) {
          float p = __shfl_xor(v, 1);
          float a = v * sigm(v) * p;
          float a2 = __shfl_xor(a, 2);
          if ((lr & 3) == 0)
            *(u32*)&Cb[(size_t)row * DFF + (col >> 1)] = pk2(a, a2);
        } else {  // EPI == 4
          __builtin_nontemporal_store(v, &Cf[(size_t)row * ldc + col]);
        }
      }
    }
}

template<int TM, int TN, int EPI>
__global__ __launch_bounds__(256, 5) void k_gemm_v3(
    const u16* __restrict__ A, const u16* __restrict__ B,
    float* __restrict__ Cf, u16* __restrict__ Cb, const float* __restrict__ Res,
    int NB, int K, int ldc, float alpha)
{
  __shared__ __align__(16) char smem[(TM + TN) * 128];
  v3_body<TM, TN, EPI>(blockIdx.x, gridDim.x, smem, A, B, Cf, Cb, Res,
                       NB, K, ldc, alpha);
}

// ---------------------------------------------------------------------------
// Weight transpose+convert body: fp32 [R,C] -> bf16 [C,R]; bid >= 12800
// flat-converts W_route. bid in [0, 14848).
// ---------------------------------------------------------------------------
static __device__ __forceinline__ void transpose_body(
    int bid, char* smem,
    const float* Wi, const float* Wo, const float* Wg, const float* Wu,
    const float* Wd, const float* Wr,
    u16* WiT, u16* WoT, u16* WguT, u16* WdT, u16* WrB)
{
  if (bid >= 12800) {
    int i = (bid - 12800) * 256 + threadIdx.x;
    conv_group(i, Wr, WrB);
    return;
  }
  const float* src; u16* dst; int R, C, t0, mul, add;
  if (bid < 256)       { src = Wi; dst = WiT;  R = 1024; C = 256;  t0 = bid;        mul = 1; add = 0; }
  else if (bid < 512)  { src = Wo; dst = WoT;  R = 256;  C = 1024; t0 = bid - 256;  mul = 1; add = 0; }
  else if (bid < 4608) { src = Wg; dst = WguT; R = 1024; C = 4096; t0 = bid - 512;  mul = 2; add = 0; }
  else if (bid < 8704) { src = Wu; dst = WguT; R = 1024; C = 4096; t0 = bid - 4608; mul = 2; add = 1; }
  else                 { src = Wd; dst = WdT;  R = 4096; C = 1024; t0 = bid - 8704; mul = 1; add = 0; }
  int tC = C >> 5;
  int r0 = (t0 / tC) << 5, c0 = (t0 % tC) << 5;
  float (*tile)[33] = (float(*)[33])smem;
  int ty = threadIdx.x >> 3;
  int tx = (threadIdx.x & 7) << 2;
  float4 v = *(const float4*)&src[(size_t)(r0 + ty) * C + c0 + tx];
  tile[ty][tx] = v.x; tile[ty][tx + 1] = v.y; tile[ty][tx + 2] = v.z; tile[ty][tx + 3] = v.w;
  __syncthreads();
  float a = tile[tx][ty], b = tile[tx + 1][ty], c = tile[tx + 2][ty], d = tile[tx + 3][ty];
  *(uint2*)&dst[((size_t)(c0 + ty) * mul + add) * R + r0 + tx] = make_uint2(pk2(a, b), pk2(c, d));
}

__global__ void k_transpose_layer(
    const float* __restrict__ Wi, const float* __restrict__ Wo,
    const float* __restrict__ Wg, const float* __restrict__ Wu,
    const float* __restrict__ Wd, const float* __restrict__ Wr,
    u16* __restrict__ WiT, u16* __restrict__ WoT,
    u16* __restrict__ WguT, u16* __restrict__ WdT, u16* __restrict__ WrB)
{
  __shared__ __align__(16) char smem[4224];
  transpose_body(blockIdx.x, smem, Wi, Wo, Wg, Wu, Wd, Wr,
                 WiT, WoT, WguT, WdT, WrB);
}

// ---------------------------------------------------------------------------
// 64x64 GEMM device body (NT, bf16), Cf = acc.
// ---------------------------------------------------------------------------
static __device__ __forceinline__ void gemm64_body(
    const u16* A, const u16* B, float* Cf,
    int m0, int n0, int K, int lda, int ldb, int ldc, char* smem)
{
  u16* As = (u16*)smem;
  u16* Bs = (u16*)(smem + 64 * 64 * 2);
  const int tid = threadIdx.x;
  const int l = tid & 63;
  const int wv = tid >> 6;
  const int wm = wv >> 1, wn = wv & 1;
  const int lr = l & 15, lg = l >> 4;

  uint4 aR[2], bR[2];
  f32x4 acc[2][2] = {};
  const int nk = K >> 6;

  auto loadAB = [&](int k0) {
#pragma unroll
    for (int c = 0; c < 2; ++c) {
      int id = c * 256 + tid;
      int row = id >> 3, kc = (id & 7) << 3;
      aR[c] = *(const uint4*)&A[(size_t)(m0 + row) * lda + k0 + kc];
      bR[c] = *(const uint4*)&B[(size_t)(n0 + row) * ldb + k0 + kc];
    }
  };
  auto stage = [&]() {
#pragma unroll
    for (int c = 0; c < 2; ++c) {
      int id = c * 256 + tid;
      int row = id >> 3, kc = (id & 7) << 3;
      *(uint4*)&As[row * 64 + kc] = aR[c];
      *(uint4*)&Bs[row * 64 + kc] = bR[c];
    }
  };

  loadAB(0);
  for (int s = 0; s < nk; ++s) {
    __syncthreads();
    stage();
    __syncthreads();
    if (s + 1 < nk) loadAB((s + 1) << 6);
#pragma unroll
    for (int kk = 0; kk < 2; ++kk) {
      bf16x8 fa[2], fb[2];
#pragma unroll
      for (int mi = 0; mi < 2; ++mi)
        fa[mi] = *(const bf16x8*)&As[(wm * 32 + mi * 16 + lr) * 64 + kk * 32 + lg * 8];
#pragma unroll
      for (int ni = 0; ni < 2; ++ni)
        fb[ni] = *(const bf16x8*)&Bs[(wn * 32 + ni * 16 + lr) * 64 + kk * 32 + lg * 8];
#pragma unroll
      for (int mi = 0; mi < 2; ++mi)
#pragma unroll
        for (int ni = 0; ni < 2; ++ni)
          acc[mi][ni] = __builtin_amdgcn_mfma_f32_16x16x32_bf16(fa[mi], fb[ni], acc[mi][ni], 0, 0, 0);
    }
  }

#pragma unroll
  for (int mi = 0; mi < 2; ++mi)
#pragma unroll
    for (int ni = 0; ni < 2; ++ni) {
      int col = n0 + wn * 32 + ni * 16 + lr;
#pragma unroll
      for (int j = 0; j < 4; ++j) {
        int row = m0 + wm * 32 + mi * 16 + lg * 4 + j;
        Cf[(size_t)row * ldc + col] = acc[mi][ni][j];
      }
    }
}

__global__ __launch_bounds__(256, 6) void k_gemm64(
    const u16* __restrict__ A, const u16* __restrict__ B,
    float* __restrict__ Cf, int K, int lda, int ldb, int ldc)
{
  __shared__ __align__(16) char smem[16384];
  gemm64_body(A, B, Cf, blockIdx.x * 64, blockIdx.y * 64, K, lda, ldb, ldc, smem);
}

// ---------------------------------------------------------------------------
// Fused head-of-layer: [0,512) scores GEMM; [512,640) xin; [640,1152) scan_a.
// ---------------------------------------------------------------------------
__global__ __launch_bounds__(256, 5) void k_head_fused(
    const u16* __restrict__ x_bf, const u16* __restrict__ WrB,
    float* __restrict__ scores,
    const u16* __restrict__ WiT, float* __restrict__ xin,
    const float* __restrict__ x_f, float* __restrict__ E,
    const float* __restrict__ sgw, const float* __restrict__ sgb,
    const float* __restrict__ sdec)
{
  __shared__ __align__(16) char smem[32768];
  int bid = blockIdx.x;
  if (bid < 512) {
    v3_body<128, 128, 0>(bid, 512, smem, x_bf, WrB, scores, nullptr, nullptr,
                         NCELL, DMODEL, NCELL, 0.03125f);
    return;
  }
  if (bid < 640) {
    int b2 = bid - 512;
    gemm64_body(x_bf, WiT, xin, (b2 & 31) * 64, (b2 >> 5) * 64,
                DMODEL, DMODEL, DMODEL, DCELL, smem);
    return;
  }
  int tid = (bid - 640) * 256 + threadIdx.x;   // 131072 = 8b * 16c * 1024d
  int d = tid & 1023, bc = tid >> 10;
  int b = bc >> 4, c = bc & 15;
  float dec = sigm(sdec[0]);
  dec = fminf(fmaxf(dec, 0.01f), 0.99f);
  float gw = sgw[d], gb = sgb[d];
  size_t base = ((size_t)b * 256 + c * 16) * DMODEL + d;
  float h = 0.f;
  for (int t = 0; t < 16; ++t) {
    float xv = x_f[base + (size_t)t * DMODEL];
    h = h * dec + sigm(xv * gw + gb) * xv;
  }
  E[tid] = h;
}

// ---------------------------------------------------------------------------
// Fused: [0,512) Wd GEMM (residual); [512,15360) next-layer weight prep.
// ---------------------------------------------------------------------------
__global__ __launch_bounds__(256, 6) void k_wd_prep(
    const u16* __restrict__ act, const u16* __restrict__ WdT_cur,
    float* __restrict__ x_f, u16* __restrict__ x_bf,
    const float* __restrict__ Wi, const float* __restrict__ Wo,
    const float* __restrict__ Wg, const float* __restrict__ Wu,
    const float* __restrict__ Wd, const float* __restrict__ Wr,
    u16* __restrict__ WiT, u16* __restrict__ WoT,
    u16* __restrict__ WguT, u16* __restrict__ WdT_nxt, u16* __restrict__ WrB)
{
  __shared__ __align__(16) char smem[16384];
  int bid = blockIdx.x;
  if (bid < 512) {
    v3_body<64, 64, 1>(bid, 512, smem, act, WdT_cur, x_f, x_bf, x_f,
                       DMODEL, DFF, DMODEL, 1.0f);
  } else {
    transpose_body(bid - 512, smem, Wi, Wo, Wg, Wu, Wd, Wr,
                   WiT, WoT, WguT, WdT_nxt, WrB);
  }
}

// Streaming copy pad[row][0:NVOCAB] -> out[row][*], NT load+store.
__global__ __launch_bounds__(256) void k_copy_out(
    const float* __restrict__ pad, float* __restrict__ out)
{
  int row = blockIdx.x;
  const float* s = pad + (size_t)row * VPAD_LD;
  float* d = out + (size_t)row * NVOCAB;
  int t = threadIdx.x;
  int head = (int)((16 - (((size_t)d) & 15)) & 15) >> 2;
  if (t < head) d[t] = s[t];
  int nb = (NVOCAB - head) >> 2;
  const float* sb = s + head;
  float* db = d + head;
  for (int i = t; i < nb; i += 256) {
    f32x4 v;
    v.x = __builtin_nontemporal_load(&sb[i * 4 + 0]);
    v.y = __builtin_nontemporal_load(&sb[i * 4 + 1]);
    v.z = __builtin_nontemporal_load(&sb[i * 4 + 2]);
    v.w = __builtin_nontemporal_load(&sb[i * 4 + 3]);
    __builtin_nontemporal_store(v, (f32x4*)&db[i * 4]);
  }
  int t0 = head + nb * 4;
  int rem = NVOCAB - t0;
  if (t < rem) d[t0 + t] = s[t0 + t];
}

// ---------------------------------------------------------------------------
// Fused top-8 + softmax + readout. Block = 4 rows.
// ---------------------------------------------------------------------------
__global__ __launch_bounds__(256) void k_cell_fused(
    const float* __restrict__ scores, const float* __restrict__ cells,
    const float* __restrict__ xin, u16* __restrict__ rb)
{
  __shared__ float sw[4][8];
  __shared__ int si[4][8];
  int row0 = blockIdx.x * 4;
  int wvid = threadIdx.x >> 6;
  int row = row0 + wvid;
  int l = threadIdx.x & 63;
  const float* s = scores + (size_t)row * NCELL;
  float v[8]; int ix[8];
#pragma unroll
  for (int i = 0; i < 8; ++i) { v[i] = -3.4e38f; ix[i] = 0x7fffffff; }
  for (int j = 0; j < 64; ++j) {
    float x = s[j * 64 + l];
    if (x > v[7]) {
      v[7] = x; ix[7] = j * 64 + l;
#pragma unroll
      for (int q = 7; q > 0; --q) {
        if (v[q] > v[q - 1]) {
          float tv = v[q]; v[q] = v[q - 1]; v[q - 1] = tv;
          int tt = ix[q]; ix[q] = ix[q - 1]; ix[q - 1] = tt;
        }
      }
    }
  }
  float ov[8]; int oi[8];
#pragma unroll
  for (int r = 0; r < 8; ++r) {
    float bv = v[0]; int bi = ix[0];
#pragma unroll
    for (int o = 32; o > 0; o >>= 1) {
      float tv = __shfl_xor(bv, o);
      int tb = __shfl_xor(bi, o);
      if (tv > bv || (tv == bv && tb < bi)) { bv = tv; bi = tb; }
    }
    ov[r] = bv; oi[r] = bi;
    if (bi == ix[0]) {
#pragma unroll
      for (int q = 0; q < 7; ++q) { v[q] = v[q + 1]; ix[q] = ix[q + 1]; }
      v[7] = -3.4e38f; ix[7] = 0x7fffffff;
    }
  }
  if (l == 0) {
    float m = ov[0], sum = 0.f, e[8];
#pragma unroll
    for (int r = 0; r < 8; ++r) { e[r] = __expf(ov[r] - m); sum += e[r]; }
    float inv = 1.0f / sum;
#pragma unroll
    for (int r = 0; r < 8; ++r) { sw[wvid][r] = e[r] * inv; si[wvid][r] = oi[r]; }
  }
  __syncthreads();
  int d = threadIdx.x;
#pragma unroll
  for (int r = 0; r < 4; ++r) {
    int rr = row0 + r;
    float acc = xin[(size_t)rr * DCELL + d];
#pragma unroll
    for (int k = 0; k < 8; ++k)
      acc += sw[r][k] * cells[(size_t)si[r][k] * DCELL + d];
    rb[(size_t)rr * DCELL + d] = f2bf(acc);
  }
}

// ---------------------------------------------------------------------------
// Fused scan_b + double rmsnorm, single pair-reduction per t-step (R14 ver).
// ---------------------------------------------------------------------------
__global__ __launch_bounds__(1024) void k_scan_norm(
    float* __restrict__ x_f, const float* __restrict__ co,
    const float* __restrict__ E, u16* __restrict__ h2b,
    const float* __restrict__ sgw, const float* __restrict__ sgb,
    const float* __restrict__ ssc, const float* __restrict__ sdec,
    const float* __restrict__ csc, const float* __restrict__ nw,
    const float* __restrict__ fw)
{
  __shared__ float sm[32];
  int b = blockIdx.x >> 4, c = blockIdx.x & 15;
  int d = threadIdx.x;
  float dec = sigm(sdec[0]);
  dec = fminf(fmaxf(dec, 0.01f), 0.99f);
  float d2 = dec * dec, d4 = d2 * d2, d8 = d4 * d4;
  float d16 = d8 * d8;
  float cs = csc[0];
  float gw = sgw[d], gb = sgb[d], sc = ssc[d];
  float nwd = nw[d], fwd = fw[d];
  float h = 0.f;
  for (int cc = 0; cc < c; ++cc) h = h * d16 + E[((b << 4) + cc) * 1024 + d];
  size_t base = ((size_t)b * 256 + c * 16) * DMODEL + d;
  for (int t = 0; t < 16; ++t) {
    size_t o = base + (size_t)t * DMODEL;
    float xv = x_f[o];
    float g = sigm(xv * gw + gb);
    h = h * dec + g * xv;
    float pre = xv + cs * co[o] + h * sc;
    float pn = pre * nwd;
    float s1 = pre * pre, s2 = pn * pn;
    blockReducePair1024(s1, s2, sm);
    float inv = rsqrtf(s1 * (1.0f / DMODEL) + 1e-6f);
    float x1 = pre * inv * nwd;
    float inv2 = rsqrtf(inv * inv * s2 * (1.0f / DMODEL) + 1e-6f);
    x_f[o] = x1;
    h2b[o] = f2bf(x1 * inv2 * fwd);
  }
}

__global__ void k_embed_norm(const int* __restrict__ tok, const float* __restrict__ emb,
                             const float* __restrict__ w, float* __restrict__ xf,
                             u16* __restrict__ xb)
{
  int row = blockIdx.x;
  int t = tok[row];
  float4 v = ((const float4*)(emb + (size_t)t * DMODEL))[threadIdx.x];
  float tot = blockReduceSum(v.x * v.x + v.y * v.y + v.z * v.z + v.w * v.w);
  float inv = rsqrtf(tot * (1.0f / DMODEL) + 1e-6f);
  int d0 = threadIdx.x << 2;
  float4 wv = *(const float4*)(w + d0);
  float4 o;
  o.x = v.x * inv * wv.x; o.y = v.y * inv * wv.y;
  o.z = v.z * inv * wv.z; o.w = v.w * inv * wv.w;
  *(float4*)(xf + (size_t)row * DMODEL + d0) = o;
  *(uint2*)(xb + (size_t)row * DMODEL + d0) = make_uint2(pk2(o.x, o.y), pk2(o.z, o.w));
}

// Tail fused: blocks [0,2048) rmsnorm(x_f)*ln_out -> xf_bf;
// blocks [2048, ...) embed fp32->bf16 flat convert.
__global__ __launch_bounds__(256) void k_tail(
    const float* __restrict__ xf, const float* __restrict__ w,
    u16* __restrict__ ob, const float* __restrict__ emb,
    u16* __restrict__ emb_bf)
{
  int bid = blockIdx.x;
  if (bid >= 2048) {
    int i = (bid - 2048) * 256 + threadIdx.x;
    if (i >= NCONV8) return;
    conv_group(i, emb, emb_bf);
    return;
  }
  int row = bid;
  float4 v = ((const float4*)(xf + (size_t)row * DMODEL))[threadIdx.x];
  float tot = blockReduceSum(v.x * v.x + v.y * v.y + v.z * v.z + v.w * v.w);
  float inv = rsqrtf(tot * (1.0f / DMODEL) + 1e-6f);
  int d0 = threadIdx.x << 2;
  float4 wv = *(const float4*)(w + d0);
  *(uint2*)(ob + (size_t)row * DMODEL + d0) =
      make_uint2(pk2(v.x * inv * wv.x, v.y * inv * wv.y),
                 pk2(v.z * inv * wv.z, v.w * inv * wv.w));
}

// ---------------------------------------------------------------------------
extern "C" void kernel_launch(void* const* d_in, const int* in_sizes, int n_in,
                              void* d_out, int out_size, void* d_ws, size_t ws_size,
                              hipStream_t stream)
{
  const int*   tokens  = (const int*)d_in[0];
  const float* embed   = (const float*)d_in[1];
  const float* ln_in_w = (const float*)d_in[2];
  const float* ln_out_w= (const float*)d_in[3];
  const float* W_route = (const float*)d_in[4];
  const float* cells   = (const float*)d_in[5];
  const float* W_in    = (const float*)d_in[6];
  const float* W_out   = (const float*)d_in[7];
  const float* sdec    = (const float*)d_in[8];
  const float* sgw     = (const float*)d_in[9];
  const float* sgb     = (const float*)d_in[10];
  const float* ssc     = (const float*)d_in[11];
  const float* csc     = (const float*)d_in[12];
  const float* Wg      = (const float*)d_in[13];
  const float* Wu      = (const float*)d_in[14];
  const float* Wd      = (const float*)d_in[15];
  const float* ffw     = (const float*)d_in[16];
  const float* nrw     = (const float*)d_in[17];
  float* out = (float*)d_out;
  (void)in_sizes; (void)n_in; (void)out_size;

  char* ws = (char*)d_ws;
  size_t off = 0;
  auto alloc = [&](size_t bytes) -> void* {
    void* p = ws + off;
    off += (bytes + 255) & ~(size_t)255;
    return p;
  };

  // ---- epoch 1 (layer loop scratch) ----
  float* scores = (float*)alloc((size_t)MTOK * NCELL * 4);
  u16*  act_bf  = (u16*)alloc((size_t)MTOK * DFF * 2);
  float* x_f    = (float*)alloc((size_t)MTOK * DMODEL * 4);
  u16*  x_bf    = (u16*)alloc((size_t)MTOK * DMODEL * 2);
  u16*  h2_bf   = (u16*)alloc((size_t)MTOK * DMODEL * 2);
  float* xin    = (float*)alloc((size_t)MTOK * DCELL * 4);
  u16*  r_bf    = (u16*)alloc((size_t)MTOK * DCELL * 2);
  float* cellout= (float*)alloc((size_t)MTOK * DMODEL * 4);
  u16*  WiT     = (u16*)alloc((size_t)DCELL * DMODEL * 2);
  u16*  WoT     = (u16*)alloc((size_t)DMODEL * DCELL * 2);
  u16*  WguT    = (u16*)alloc((size_t)8192 * DMODEL * 2);
  u16*  WdTa    = (u16*)alloc((size_t)DMODEL * DFF * 2);
  u16*  WdTb    = (u16*)alloc((size_t)DMODEL * DFF * 2);   // double-buffered
  u16*  WrB     = (u16*)alloc((size_t)NCELL * DMODEL * 2);
  float* E      = (float*)alloc((size_t)131072 * 4);
  // ---- persistent tail (above embed_bf's 103 MB overlay span) ----
  if (off < ((size_t)108 << 20)) off = (size_t)108 << 20;
  u16*  xf_bf   = (u16*)alloc((size_t)MTOK * DMODEL * 2);
  float* vpad   = (float*)alloc((size_t)MTOK * VPAD_LD * 4);   // 412 MB
  size_t need_pad = off;
  // ---- epoch 2 overlay (written only after layer loop) ----
  u16*  embed_bf = (u16*)ws;

  const bool use_pad = (ws_size >= need_pad);

  k_embed_norm<<<MTOK, 256, 0, stream>>>(tokens, embed, ln_in_w, x_f, x_bf);
  // layer 0 weight prep
  k_transpose_layer<<<14848, 256, 0, stream>>>(W_in, W_out, Wg, Wu, Wd, W_route,
                                               WiT, WoT, WguT, WdTa, WrB);

  for (int lay = 0; lay < 8; ++lay) {
    const float* cells_l = cells + (size_t)lay * NCELL * DCELL;
    u16* WdT_cur = (lay & 1) ? WdTb : WdTa;
    u16* WdT_nxt = (lay & 1) ? WdTa : WdTb;

    // head: scores GEMM + xin GEMM + scan pass A (fused, independent)
    k_head_fused<<<1152, 256, 0, stream>>>(x_bf, WrB, scores, WiT, xin, x_f, E,
        sgw + lay * DMODEL, sgb + lay * DMODEL, sdec + lay);
    // top-8 + softmax + readout
    k_cell_fused<<<512, 256, 0, stream>>>(scores, cells_l, xin, r_bf);
    // cell_out = readout @ W_out
    k_gemm64<<<dim3(32, 16), 256, 0, stream>>>(r_bf, WoT, cellout,
        DCELL, DCELL, DCELL, DMODEL);
    // scan pass B + both rmsnorms (single pair-reduction per t)
    k_scan_norm<<<128, 1024, 0, stream>>>(x_f, cellout, E, h2_bf,
        sgw + lay * DMODEL, sgb + lay * DMODEL, ssc + lay * DMODEL,
        sdec + lay, csc + lay, nrw + lay * DMODEL, ffw + lay * DMODEL);
    // act = silu(g)*u fused epilogue
    k_gemm_v3<128, 128, 3><<<1024, 256, 0, stream>>>(h2_bf, WguT, nullptr, act_bf,
        nullptr, 8192, DMODEL, 0, 1.0f);
    // x = x + act @ Wd ; fused with next layer's weight prep
    if (lay < 7) {
      int nl = lay + 1;
      k_wd_prep<<<15360, 256, 0, stream>>>(act_bf, WdT_cur, x_f, x_bf,
          W_in  + (size_t)nl * DMODEL * DCELL,
          W_out + (size_t)nl * DCELL * DMODEL,
          Wg    + (size_t)nl * DMODEL * DFF,
          Wu    + (size_t)nl * DMODEL * DFF,
          Wd    + (size_t)nl * DFF * DMODEL,
          W_route + (size_t)nl * NCELL * DMODEL,
          WiT, WoT, WguT, WdT_nxt, WrB);
    } else {
      k_gemm_v3<64, 64, 1><<<512, 256, 0, stream>>>(act_bf, WdT_cur, x_f, x_bf,
          x_f, DMODEL, DFF, DMODEL, 1.0f);
    }
  }

  // tail: final norm + embed bf16 convert (fused, right before vocab GEMM)
  k_tail<<<2048 + 25129, 256, 0, stream>>>(x_f, ln_out_w, xf_bf, embed, embed_bf);
  // logits GEMM (TM=128 x TN=128, NT f32 stores) -> aligned pad -> copy
  if (use_pad) {
    k_gemm_v3<128, 128, 4><<<6288, 256, 0, stream>>>(xf_bf, embed_bf, vpad, nullptr,
        nullptr, NVOCAB, DMODEL, VPAD_LD, 1.0f);
    k_copy_out<<<MTOK, 256, 0, stream>>>(vpad, out);
  } else {
    k_gemm_v3<128, 128, 2><<<6288, 256, 0, stream>>>(xf_bf, embed_bf, out, nullptr,
        nullptr, NVOCAB, DMODEL, NVOCAB, 1.0f);
  }
}

// Round 20
// 2369.374 us; speedup vs baseline: 1.2916x; 1.2916x over previous
//
#include <hip/hip_runtime.h>
#include <stdint.h>

typedef __attribute__((ext_vector_type(8))) short bf16x8;
typedef __attribute__((ext_vector_type(4))) float f32x4;
typedef unsigned short u16;
typedef unsigned int u32;

#define MTOK 2048
#define DMODEL 1024
#define NCELL 4096
#define DCELL 256
#define DFF 4096
#define NVOCAB 50257
#define VPAD_LD 50304          // 393 * 128, aligned pad leading dim
#define NCONV8 (NVOCAB * 128)  // embed 8-elem groups

static __device__ __forceinline__ u16 f2bf(float f) {
  u32 u = __builtin_bit_cast(u32, f);
  u = (u + 0x7FFFu + ((u >> 16) & 1u)) >> 16;
  return (u16)u;
}
static __device__ __forceinline__ u32 pk2(float a, float b) {
  return (u32)f2bf(a) | ((u32)f2bf(b) << 16);
}
static __device__ __forceinline__ float sigm(float x) { return 1.0f / (1.0f + __expf(-x)); }

// async global->LDS, 16 B per lane; lds dest = wave-uniform base + lane*16
static __device__ __forceinline__ void glds16(const void* g, void* l) {
  __builtin_amdgcn_global_load_lds(
      (const __attribute__((address_space(1))) void*)g,
      (__attribute__((address_space(3))) void*)l, 16, 0, 0);
}

static __device__ __forceinline__ float blockReduceSum(float v) {
#pragma unroll
  for (int o = 32; o > 0; o >>= 1) v += __shfl_xor(v, o);
  __shared__ float sm[4];
  __syncthreads();
  if ((threadIdx.x & 63) == 0) sm[threadIdx.x >> 6] = v;
  __syncthreads();
  return sm[0] + sm[1] + sm[2] + sm[3];
}

// 1024-thread block reduce of a PAIR (16 waves)
static __device__ __forceinline__ void blockReducePair1024(
    float& a, float& b, float* sm)
{
#pragma unroll
  for (int o = 32; o > 0; o >>= 1) { a += __shfl_xor(a, o); b += __shfl_xor(b, o); }
  int wv = threadIdx.x >> 6;
  if ((threadIdx.x & 63) == 0) { sm[wv * 2] = a; sm[wv * 2 + 1] = b; }
  __syncthreads();
  float ra = 0.f, rb = 0.f;
#pragma unroll
  for (int i = 0; i < 16; ++i) { ra += sm[i * 2]; rb += sm[i * 2 + 1]; }
  __syncthreads();
  a = ra; b = rb;
}

// embed fp32 -> bf16, one 8-elem group per thread
static __device__ __forceinline__ void conv_group(
    int i, const float* emb, u16* emb_bf)
{
  const float4* s = (const float4*)(emb + (size_t)i * 8);
  float4 a = s[0], b = s[1];
  *(uint4*)(emb_bf + (size_t)i * 8) =
      make_uint4(pk2(a.x, a.y), pk2(a.z, a.w), pk2(b.x, b.y), pk2(b.z, b.w));
}

// ---------------------------------------------------------------------------
// m97-style GEMM device body: C[2048,N] = A[2048,K](bf16) x B[N,K]^T(bf16)
// EPI 0: Cf = alpha*acc          EPI 1: residual r=Res+acc -> Cf,f2bf->Cb
// EPI 2: predicated col<NB       EPI 3: fused SwiGLU -> bf16 Cb
// EPI 4: nontemporal aligned f32 store (full-lane coverage; vpad)
// ---------------------------------------------------------------------------
template<int TM, int TN, int EPI>
static __device__ __forceinline__ void v3_body(
    int bid, int T, char* smem,
    const u16* A, const u16* B,
    float* Cf, u16* Cb, const float* Res,
    int NB, int K, int ldc, float alpha)
{
  u16* As = (u16*)smem;
  u16* Bs = (u16*)(smem + TM * 128);
  constexpr int MI = TM / 32;
  constexpr int NI = TN / 32;
  constexpr int ACH = TM / 32;
  constexpr int BCH = TN / 32;
  constexpr int MB = 2048 / TM;
  const int tid = threadIdx.x;
  const int w = (bid & 7) * (T >> 3) + (bid >> 3);
  const int m0 = (w % MB) * TM;
  const int n0 = (w / MB) * TN;
  const int l = tid & 63;
  const int wv = tid >> 6;
  const int wm = wv >> 1, wn = wv & 1;
  const int lr = l & 15, lg = l >> 4;
  const int wbase = tid & ~63;

  f32x4 acc[MI][NI] = {};

  const int row_ = tid >> 3;
  const int kc_ = (tid & 7) << 3;
  const int nk = K >> 6;

  for (int s = 0; s < nk; ++s) {
    const int k0 = s << 6;
#pragma unroll
    for (int c = 0; c < ACH; ++c) {
      int row = c * 32 + row_;
      glds16(&A[(size_t)(m0 + row) * K + k0 + kc_],
             &As[(size_t)(c * 256 + wbase) * 8]);
    }
#pragma unroll
    for (int c = 0; c < BCH; ++c) {
      int row = c * 32 + row_;
      int gr = n0 + row; if (gr > NB - 1) gr = NB - 1;
      glds16(&B[(size_t)gr * K + k0 + kc_],
             &Bs[(size_t)(c * 256 + wbase) * 8]);
    }
    __syncthreads();
#pragma unroll
    for (int kk = 0; kk < 2; ++kk) {
      bf16x8 fa[MI], fb[NI];
#pragma unroll
      for (int mi = 0; mi < MI; ++mi)
        fa[mi] = *(const bf16x8*)&As[(wm * (TM / 2) + mi * 16 + lr) * 64 + kk * 32 + lg * 8];
#pragma unroll
      for (int ni = 0; ni < NI; ++ni)
        fb[ni] = *(const bf16x8*)&Bs[(wn * (TN / 2) + ni * 16 + lr) * 64 + kk * 32 + lg * 8];
#pragma unroll
      for (int mi = 0; mi < MI; ++mi)
#pragma unroll
        for (int ni = 0; ni < NI; ++ni)
          acc[mi][ni] = __builtin_amdgcn_mfma_f32_16x16x32_bf16(fa[mi], fb[ni], acc[mi][ni], 0, 0, 0);
    }
    __syncthreads();
  }

#pragma unroll
  for (int mi = 0; mi < MI; ++mi)
#pragma unroll
    for (int ni = 0; ni < NI; ++ni) {
      int col = n0 + wn * (TN / 2) + ni * 16 + lr;
#pragma unroll
      for (int j = 0; j < 4; ++j) {
        int row = m0 + wm * (TM / 2) + mi * 16 + lg * 4 + j;
        float v = acc[mi][ni][j];
        if constexpr (EPI == 0) {
          Cf[(size_t)row * ldc + col] = v * alpha;
        } else if constexpr (EPI == 1) {
          size_t off = (size_t)row * ldc + col;
          float r = Res[off] + v;
          Cf[off] = r;
          Cb[off] = f2bf(r);
        } else if constexpr (EPI == 2) {
          if (col < NB) Cf[(size_t)row * ldc + col] = v;
        } else if constexpr (EPI == 3) {
          float p = __shfl_xor(v, 1);
          float a = v * sigm(v) * p;
          float a2 = __shfl_xor(a, 2);
          if ((lr & 3) == 0)
            *(u32*)&Cb[(size_t)row * DFF + (col >> 1)] = pk2(a, a2);
        } else {  // EPI == 4
          __builtin_nontemporal_store(v, &Cf[(size_t)row * ldc + col]);
        }
      }
    }
}

template<int TM, int TN, int EPI>
__global__ __launch_bounds__(256, 4) void k_gemm_v3(
    const u16* __restrict__ A, const u16* __restrict__ B,
    float* __restrict__ Cf, u16* __restrict__ Cb, const float* __restrict__ Res,
    int NB, int K, int ldc, float alpha)
{
  __shared__ __align__(16) char smem[(TM + TN) * 128];
  v3_body<TM, TN, EPI>(blockIdx.x, gridDim.x, smem, A, B, Cf, Cb, Res,
                       NB, K, ldc, alpha);
}

// ---------------------------------------------------------------------------
// Weight transpose+convert body: fp32 [R,C] -> bf16 [C,R]; bid >= 12800
// flat-converts W_route. bid in [0, 14848).
// ---------------------------------------------------------------------------
static __device__ __forceinline__ void transpose_body(
    int bid, char* smem,
    const float* Wi, const float* Wo, const float* Wg, const float* Wu,
    const float* Wd, const float* Wr,
    u16* WiT, u16* WoT, u16* WguT, u16* WdT, u16* WrB)
{
  if (bid >= 12800) {
    int i = (bid - 12800) * 256 + threadIdx.x;
    conv_group(i, Wr, WrB);
    return;
  }
  const float* src; u16* dst; int R, C, t0, mul, add;
  if (bid < 256)       { src = Wi; dst = WiT;  R = 1024; C = 256;  t0 = bid;        mul = 1; add = 0; }
  else if (bid < 512)  { src = Wo; dst = WoT;  R = 256;  C = 1024; t0 = bid - 256;  mul = 1; add = 0; }
  else if (bid < 4608) { src = Wg; dst = WguT; R = 1024; C = 4096; t0 = bid - 512;  mul = 2; add = 0; }
  else if (bid < 8704) { src = Wu; dst = WguT; R = 1024; C = 4096; t0 = bid - 4608; mul = 2; add = 1; }
  else                 { src = Wd; dst = WdT;  R = 4096; C = 1024; t0 = bid - 8704; mul = 1; add = 0; }
  int tC = C >> 5;
  int r0 = (t0 / tC) << 5, c0 = (t0 % tC) << 5;
  float (*tile)[33] = (float(*)[33])smem;
  int ty = threadIdx.x >> 3;
  int tx = (threadIdx.x & 7) << 2;
  float4 v = *(const float4*)&src[(size_t)(r0 + ty) * C + c0 + tx];
  tile[ty][tx] = v.x; tile[ty][tx + 1] = v.y; tile[ty][tx + 2] = v.z; tile[ty][tx + 3] = v.w;
  __syncthreads();
  float a = tile[tx][ty], b = tile[tx + 1][ty], c = tile[tx + 2][ty], d = tile[tx + 3][ty];
  *(uint2*)&dst[((size_t)(c0 + ty) * mul + add) * R + r0 + tx] = make_uint2(pk2(a, b), pk2(c, d));
}

__global__ void k_transpose_layer(
    const float* __restrict__ Wi, const float* __restrict__ Wo,
    const float* __restrict__ Wg, const float* __restrict__ Wu,
    const float* __restrict__ Wd, const float* __restrict__ Wr,
    u16* __restrict__ WiT, u16* __restrict__ WoT,
    u16* __restrict__ WguT, u16* __restrict__ WdT, u16* __restrict__ WrB)
{
  __shared__ __align__(16) char smem[4224];
  transpose_body(blockIdx.x, smem, Wi, Wo, Wg, Wu, Wd, Wr,
                 WiT, WoT, WguT, WdT, WrB);
}

// ---------------------------------------------------------------------------
// 64x64 GEMM device body (NT, bf16), Cf = acc.
// ---------------------------------------------------------------------------
static __device__ __forceinline__ void gemm64_body(
    const u16* A, const u16* B, float* Cf,
    int m0, int n0, int K, int lda, int ldb, int ldc, char* smem)
{
  u16* As = (u16*)smem;
  u16* Bs = (u16*)(smem + 64 * 64 * 2);
  const int tid = threadIdx.x;
  const int l = tid & 63;
  const int wv = tid >> 6;
  const int wm = wv >> 1, wn = wv & 1;
  const int lr = l & 15, lg = l >> 4;

  uint4 aR[2], bR[2];
  f32x4 acc[2][2] = {};
  const int nk = K >> 6;

  auto loadAB = [&](int k0) {
#pragma unroll
    for (int c = 0; c < 2; ++c) {
      int id = c * 256 + tid;
      int row = id >> 3, kc = (id & 7) << 3;
      aR[c] = *(const uint4*)&A[(size_t)(m0 + row) * lda + k0 + kc];
      bR[c] = *(const uint4*)&B[(size_t)(n0 + row) * ldb + k0 + kc];
    }
  };
  auto stage = [&]() {
#pragma unroll
    for (int c = 0; c < 2; ++c) {
      int id = c * 256 + tid;
      int row = id >> 3, kc = (id & 7) << 3;
      *(uint4*)&As[row * 64 + kc] = aR[c];
      *(uint4*)&Bs[row * 64 + kc] = bR[c];
    }
  };

  loadAB(0);
  for (int s = 0; s < nk; ++s) {
    __syncthreads();
    stage();
    __syncthreads();
    if (s + 1 < nk) loadAB((s + 1) << 6);
#pragma unroll
    for (int kk = 0; kk < 2; ++kk) {
      bf16x8 fa[2], fb[2];
#pragma unroll
      for (int mi = 0; mi < 2; ++mi)
        fa[mi] = *(const bf16x8*)&As[(wm * 32 + mi * 16 + lr) * 64 + kk * 32 + lg * 8];
#pragma unroll
      for (int ni = 0; ni < 2; ++ni)
        fb[ni] = *(const bf16x8*)&Bs[(wn * 32 + ni * 16 + lr) * 64 + kk * 32 + lg * 8];
#pragma unroll
      for (int mi = 0; mi < 2; ++mi)
#pragma unroll
        for (int ni = 0; ni < 2; ++ni)
          acc[mi][ni] = __builtin_amdgcn_mfma_f32_16x16x32_bf16(fa[mi], fb[ni], acc[mi][ni], 0, 0, 0);
    }
  }

#pragma unroll
  for (int mi = 0; mi < 2; ++mi)
#pragma unroll
    for (int ni = 0; ni < 2; ++ni) {
      int col = n0 + wn * 32 + ni * 16 + lr;
#pragma unroll
      for (int j = 0; j < 4; ++j) {
        int row = m0 + wm * 32 + mi * 16 + lg * 4 + j;
        Cf[(size_t)row * ldc + col] = acc[mi][ni][j];
      }
    }
}

__global__ __launch_bounds__(256, 4) void k_gemm64(
    const u16* __restrict__ A, const u16* __restrict__ B,
    float* __restrict__ Cf, int K, int lda, int ldb, int ldc)
{
  __shared__ __align__(16) char smem[16384];
  gemm64_body(A, B, Cf, blockIdx.x * 64, blockIdx.y * 64, K, lda, ldb, ldc, smem);
}

// ---------------------------------------------------------------------------
// Fused head-of-layer: [0,512) scores GEMM; [512,640) xin; [640,1152) scan_a.
// ---------------------------------------------------------------------------
__global__ __launch_bounds__(256, 4) void k_head_fused(
    const u16* __restrict__ x_bf, const u16* __restrict__ WrB,
    float* __restrict__ scores,
    const u16* __restrict__ WiT, float* __restrict__ xin,
    const float* __restrict__ x_f, float* __restrict__ E,
    const float* __restrict__ sgw, const float* __restrict__ sgb,
    const float* __restrict__ sdec)
{
  __shared__ __align__(16) char smem[32768];
  int bid = blockIdx.x;
  if (bid < 512) {
    v3_body<128, 128, 0>(bid, 512, smem, x_bf, WrB, scores, nullptr, nullptr,
                         NCELL, DMODEL, NCELL, 0.03125f);
    return;
  }
  if (bid < 640) {
    int b2 = bid - 512;
    gemm64_body(x_bf, WiT, xin, (b2 & 31) * 64, (b2 >> 5) * 64,
                DMODEL, DMODEL, DMODEL, DCELL, smem);
    return;
  }
  int tid = (bid - 640) * 256 + threadIdx.x;   // 131072 = 8b * 16c * 1024d
  int d = tid & 1023, bc = tid >> 10;
  int b = bc >> 4, c = bc & 15;
  float dec = sigm(sdec[0]);
  dec = fminf(fmaxf(dec, 0.01f), 0.99f);
  float gw = sgw[d], gb = sgb[d];
  size_t base = ((size_t)b * 256 + c * 16) * DMODEL + d;
  float h = 0.f;
  for (int t = 0; t < 16; ++t) {
    float xv = x_f[base + (size_t)t * DMODEL];
    h = h * dec + sigm(xv * gw + gb) * xv;
  }
  E[tid] = h;
}

// ---------------------------------------------------------------------------
// Fused: [0,512) Wd GEMM (residual); [512,15360) next-layer weight prep.
// ---------------------------------------------------------------------------
__global__ __launch_bounds__(256, 4) void k_wd_prep(
    const u16* __restrict__ act, const u16* __restrict__ WdT_cur,
    float* __restrict__ x_f, u16* __restrict__ x_bf,
    const float* __restrict__ Wi, const float* __restrict__ Wo,
    const float* __restrict__ Wg, const float* __restrict__ Wu,
    const float* __restrict__ Wd, const float* __restrict__ Wr,
    u16* __restrict__ WiT, u16* __restrict__ WoT,
    u16* __restrict__ WguT, u16* __restrict__ WdT_nxt, u16* __restrict__ WrB)
{
  __shared__ __align__(16) char smem[16384];
  int bid = blockIdx.x;
  if (bid < 512) {
    v3_body<64, 64, 1>(bid, 512, smem, act, WdT_cur, x_f, x_bf, x_f,
                       DMODEL, DFF, DMODEL, 1.0f);
  } else {
    transpose_body(bid - 512, smem, Wi, Wo, Wg, Wu, Wd, Wr,
                   WiT, WoT, WguT, WdT_nxt, WrB);
  }
}

// Streaming copy pad[row][0:NVOCAB] -> out[row][*], NT load+store.
__global__ __launch_bounds__(256) void k_copy_out(
    const float* __restrict__ pad, float* __restrict__ out)
{
  int row = blockIdx.x;
  const float* s = pad + (size_t)row * VPAD_LD;
  float* d = out + (size_t)row * NVOCAB;
  int t = threadIdx.x;
  int head = (int)((16 - (((size_t)d) & 15)) & 15) >> 2;
  if (t < head) d[t] = s[t];
  int nb = (NVOCAB - head) >> 2;
  const float* sb = s + head;
  float* db = d + head;
  for (int i = t; i < nb; i += 256) {
    f32x4 v;
    v.x = __builtin_nontemporal_load(&sb[i * 4 + 0]);
    v.y = __builtin_nontemporal_load(&sb[i * 4 + 1]);
    v.z = __builtin_nontemporal_load(&sb[i * 4 + 2]);
    v.w = __builtin_nontemporal_load(&sb[i * 4 + 3]);
    __builtin_nontemporal_store(v, (f32x4*)&db[i * 4]);
  }
  int t0 = head + nb * 4;
  int rem = NVOCAB - t0;
  if (t < rem) d[t0 + t] = s[t0 + t];
}

// ---------------------------------------------------------------------------
// Fused top-8 + softmax + readout. Block = 4 rows.
// ---------------------------------------------------------------------------
__global__ __launch_bounds__(256) void k_cell_fused(
    const float* __restrict__ scores, const float* __restrict__ cells,
    const float* __restrict__ xin, u16* __restrict__ rb)
{
  __shared__ float sw[4][8];
  __shared__ int si[4][8];
  int row0 = blockIdx.x * 4;
  int wvid = threadIdx.x >> 6;
  int row = row0 + wvid;
  int l = threadIdx.x & 63;
  const float* s = scores + (size_t)row * NCELL;
  float v[8]; int ix[8];
#pragma unroll
  for (int i = 0; i < 8; ++i) { v[i] = -3.4e38f; ix[i] = 0x7fffffff; }
  for (int j = 0; j < 64; ++j) {
    float x = s[j * 64 + l];
    if (x > v[7]) {
      v[7] = x; ix[7] = j * 64 + l;
#pragma unroll
      for (int q = 7; q > 0; --q) {
        if (v[q] > v[q - 1]) {
          float tv = v[q]; v[q] = v[q - 1]; v[q - 1] = tv;
          int tt = ix[q]; ix[q] = ix[q - 1]; ix[q - 1] = tt;
        }
      }
    }
  }
  float ov[8]; int oi[8];
#pragma unroll
  for (int r = 0; r < 8; ++r) {
    float bv = v[0]; int bi = ix[0];
#pragma unroll
    for (int o = 32; o > 0; o >>= 1) {
      float tv = __shfl_xor(bv, o);
      int tb = __shfl_xor(bi, o);
      if (tv > bv || (tv == bv && tb < bi)) { bv = tv; bi = tb; }
    }
    ov[r] = bv; oi[r] = bi;
    if (bi == ix[0]) {
#pragma unroll
      for (int q = 0; q < 7; ++q) { v[q] = v[q + 1]; ix[q] = ix[q + 1]; }
      v[7] = -3.4e38f; ix[7] = 0x7fffffff;
    }
  }
  if (l == 0) {
    float m = ov[0], sum = 0.f, e[8];
#pragma unroll
    for (int r = 0; r < 8; ++r) { e[r] = __expf(ov[r] - m); sum += e[r]; }
    float inv = 1.0f / sum;
#pragma unroll
    for (int r = 0; r < 8; ++r) { sw[wvid][r] = e[r] * inv; si[wvid][r] = oi[r]; }
  }
  __syncthreads();
  int d = threadIdx.x;
#pragma unroll
  for (int r = 0; r < 4; ++r) {
    int rr = row0 + r;
    float acc = xin[(size_t)rr * DCELL + d];
#pragma unroll
    for (int k = 0; k < 8; ++k)
      acc += sw[r][k] * cells[(size_t)si[r][k] * DCELL + d];
    rb[(size_t)rr * DCELL + d] = f2bf(acc);
  }
}

// ---------------------------------------------------------------------------
// Fused scan_b + double rmsnorm, single pair-reduction per t-step (R14 ver).
// ---------------------------------------------------------------------------
__global__ __launch_bounds__(1024) void k_scan_norm(
    float* __restrict__ x_f, const float* __restrict__ co,
    const float* __restrict__ E, u16* __restrict__ h2b,
    const float* __restrict__ sgw, const float* __restrict__ sgb,
    const float* __restrict__ ssc, const float* __restrict__ sdec,
    const float* __restrict__ csc, const float* __restrict__ nw,
    const float* __restrict__ fw)
{
  __shared__ float sm[32];
  int b = blockIdx.x >> 4, c = blockIdx.x & 15;
  int d = threadIdx.x;
  float dec = sigm(sdec[0]);
  dec = fminf(fmaxf(dec, 0.01f), 0.99f);
  float d2 = dec * dec, d4 = d2 * d2, d8 = d4 * d4;
  float d16 = d8 * d8;
  float cs = csc[0];
  float gw = sgw[d], gb = sgb[d], sc = ssc[d];
  float nwd = nw[d], fwd = fw[d];
  float h = 0.f;
  for (int cc = 0; cc < c; ++cc) h = h * d16 + E[((b << 4) + cc) * 1024 + d];
  size_t base = ((size_t)b * 256 + c * 16) * DMODEL + d;
  for (int t = 0; t < 16; ++t) {
    size_t o = base + (size_t)t * DMODEL;
    float xv = x_f[o];
    float g = sigm(xv * gw + gb);
    h = h * dec + g * xv;
    float pre = xv + cs * co[o] + h * sc;
    float pn = pre * nwd;
    float s1 = pre * pre, s2 = pn * pn;
    blockReducePair1024(s1, s2, sm);
    float inv = rsqrtf(s1 * (1.0f / DMODEL) + 1e-6f);
    float x1 = pre * inv * nwd;
    float inv2 = rsqrtf(inv * inv * s2 * (1.0f / DMODEL) + 1e-6f);
    x_f[o] = x1;
    h2b[o] = f2bf(x1 * inv2 * fwd);
  }
}

__global__ void k_embed_norm(const int* __restrict__ tok, const float* __restrict__ emb,
                             const float* __restrict__ w, float* __restrict__ xf,
                             u16* __restrict__ xb)
{
  int row = blockIdx.x;
  int t = tok[row];
  float4 v = ((const float4*)(emb + (size_t)t * DMODEL))[threadIdx.x];
  float tot = blockReduceSum(v.x * v.x + v.y * v.y + v.z * v.z + v.w * v.w);
  float inv = rsqrtf(tot * (1.0f / DMODEL) + 1e-6f);
  int d0 = threadIdx.x << 2;
  float4 wv = *(const float4*)(w + d0);
  float4 o;
  o.x = v.x * inv * wv.x; o.y = v.y * inv * wv.y;
  o.z = v.z * inv * wv.z; o.w = v.w * inv * wv.w;
  *(float4*)(xf + (size_t)row * DMODEL + d0) = o;
  *(uint2*)(xb + (size_t)row * DMODEL + d0) = make_uint2(pk2(o.x, o.y), pk2(o.z, o.w));
}

// Tail fused: blocks [0,2048) rmsnorm(x_f)*ln_out -> xf_bf;
// blocks [2048, ...) embed fp32->bf16 flat convert.
__global__ __launch_bounds__(256) void k_tail(
    const float* __restrict__ xf, const float* __restrict__ w,
    u16* __restrict__ ob, const float* __restrict__ emb,
    u16* __restrict__ emb_bf)
{
  int bid = blockIdx.x;
  if (bid >= 2048) {
    int i = (bid - 2048) * 256 + threadIdx.x;
    if (i >= NCONV8) return;
    conv_group(i, emb, emb_bf);
    return;
  }
  int row = bid;
  float4 v = ((const float4*)(xf + (size_t)row * DMODEL))[threadIdx.x];
  float tot = blockReduceSum(v.x * v.x + v.y * v.y + v.z * v.z + v.w * v.w);
  float inv = rsqrtf(tot * (1.0f / DMODEL) + 1e-6f);
  int d0 = threadIdx.x << 2;
  float4 wv = *(const float4*)(w + d0);
  *(uint2*)(ob + (size_t)row * DMODEL + d0) =
      make_uint2(pk2(v.x * inv * wv.x, v.y * inv * wv.y),
                 pk2(v.z * inv * wv.z, v.w * inv * wv.w));
}

// ---------------------------------------------------------------------------
extern "C" void kernel_launch(void* const* d_in, const int* in_sizes, int n_in,
                              void* d_out, int out_size, void* d_ws, size_t ws_size,
                              hipStream_t stream)
{
  const int*   tokens  = (const int*)d_in[0];
  const float* embed   = (const float*)d_in[1];
  const float* ln_in_w = (const float*)d_in[2];
  const float* ln_out_w= (const float*)d_in[3];
  const float* W_route = (const float*)d_in[4];
  const float* cells   = (const float*)d_in[5];
  const float* W_in    = (const float*)d_in[6];
  const float* W_out   = (const float*)d_in[7];
  const float* sdec    = (const float*)d_in[8];
  const float* sgw     = (const float*)d_in[9];
  const float* sgb     = (const float*)d_in[10];
  const float* ssc     = (const float*)d_in[11];
  const float* csc     = (const float*)d_in[12];
  const float* Wg      = (const float*)d_in[13];
  const float* Wu      = (const float*)d_in[14];
  const float* Wd      = (const float*)d_in[15];
  const float* ffw     = (const float*)d_in[16];
  const float* nrw     = (const float*)d_in[17];
  float* out = (float*)d_out;
  (void)in_sizes; (void)n_in; (void)out_size;

  char* ws = (char*)d_ws;
  size_t off = 0;
  auto alloc = [&](size_t bytes) -> void* {
    void* p = ws + off;
    off += (bytes + 255) & ~(size_t)255;
    return p;
  };

  // ---- epoch 1 (layer loop scratch) ----
  float* scores = (float*)alloc((size_t)MTOK * NCELL * 4);
  u16*  act_bf  = (u16*)alloc((size_t)MTOK * DFF * 2);
  float* x_f    = (float*)alloc((size_t)MTOK * DMODEL * 4);
  u16*  x_bf    = (u16*)alloc((size_t)MTOK * DMODEL * 2);
  u16*  h2_bf   = (u16*)alloc((size_t)MTOK * DMODEL * 2);
  float* xin    = (float*)alloc((size_t)MTOK * DCELL * 4);
  u16*  r_bf    = (u16*)alloc((size_t)MTOK * DCELL * 2);
  float* cellout= (float*)alloc((size_t)MTOK * DMODEL * 4);
  u16*  WiT     = (u16*)alloc((size_t)DCELL * DMODEL * 2);
  u16*  WoT     = (u16*)alloc((size_t)DMODEL * DCELL * 2);
  u16*  WguT    = (u16*)alloc((size_t)8192 * DMODEL * 2);
  u16*  WdTa    = (u16*)alloc((size_t)DMODEL * DFF * 2);
  u16*  WdTb    = (u16*)alloc((size_t)DMODEL * DFF * 2);   // double-buffered
  u16*  WrB     = (u16*)alloc((size_t)NCELL * DMODEL * 2);
  float* E      = (float*)alloc((size_t)131072 * 4);
  // ---- persistent tail (above embed_bf's 103 MB overlay span) ----
  if (off < ((size_t)108 << 20)) off = (size_t)108 << 20;
  u16*  xf_bf   = (u16*)alloc((size_t)MTOK * DMODEL * 2);
  float* vpad   = (float*)alloc((size_t)MTOK * VPAD_LD * 4);   // 412 MB
  size_t need_pad = off;
  // ---- epoch 2 overlay (written only after layer loop) ----
  u16*  embed_bf = (u16*)ws;

  const bool use_pad = (ws_size >= need_pad);

  k_embed_norm<<<MTOK, 256, 0, stream>>>(tokens, embed, ln_in_w, x_f, x_bf);
  // layer 0 weight prep
  k_transpose_layer<<<14848, 256, 0, stream>>>(W_in, W_out, Wg, Wu, Wd, W_route,
                                               WiT, WoT, WguT, WdTa, WrB);

  for (int lay = 0; lay < 8; ++lay) {
    const float* cells_l = cells + (size_t)lay * NCELL * DCELL;
    u16* WdT_cur = (lay & 1) ? WdTb : WdTa;
    u16* WdT_nxt = (lay & 1) ? WdTa : WdTb;

    // head: scores GEMM + xin GEMM + scan pass A (fused, independent)
    k_head_fused<<<1152, 256, 0, stream>>>(x_bf, WrB, scores, WiT, xin, x_f, E,
        sgw + lay * DMODEL, sgb + lay * DMODEL, sdec + lay);
    // top-8 + softmax + readout
    k_cell_fused<<<512, 256, 0, stream>>>(scores, cells_l, xin, r_bf);
    // cell_out = readout @ W_out
    k_gemm64<<<dim3(32, 16), 256, 0, stream>>>(r_bf, WoT, cellout,
        DCELL, DCELL, DCELL, DMODEL);
    // scan pass B + both rmsnorms (single pair-reduction per t)
    k_scan_norm<<<128, 1024, 0, stream>>>(x_f, cellout, E, h2_bf,
        sgw + lay * DMODEL, sgb + lay * DMODEL, ssc + lay * DMODEL,
        sdec + lay, csc + lay, nrw + lay * DMODEL, ffw + lay * DMODEL);
    // act = silu(g)*u fused epilogue
    k_gemm_v3<128, 128, 3><<<1024, 256, 0, stream>>>(h2_bf, WguT, nullptr, act_bf,
        nullptr, 8192, DMODEL, 0, 1.0f);
    // x = x + act @ Wd ; fused with next layer's weight prep
    if (lay < 7) {
      int nl = lay + 1;
      k_wd_prep<<<15360, 256, 0, stream>>>(act_bf, WdT_cur, x_f, x_bf,
          W_in  + (size_t)nl * DMODEL * DCELL,
          W_out + (size_t)nl * DCELL * DMODEL,
          Wg    + (size_t)nl * DMODEL * DFF,
          Wu    + (size_t)nl * DMODEL * DFF,
          Wd    + (size_t)nl * DFF * DMODEL,
          W_route + (size_t)nl * NCELL * DMODEL,
          WiT, WoT, WguT, WdT_nxt, WrB);
    } else {
      k_gemm_v3<64, 64, 1><<<512, 256, 0, stream>>>(act_bf, WdT_cur, x_f, x_bf,
          x_f, DMODEL, DFF, DMODEL, 1.0f);
    }
  }

  // tail: final norm + embed bf16 convert (fused, right before vocab GEMM)
  k_tail<<<2048 + 25129, 256, 0, stream>>>(x_f, ln_out_w, xf_bf, embed, embed_bf);
  // logits GEMM (TM=128 x TN=128, NT f32 stores) -> aligned pad -> copy
  if (use_pad) {
    k_gemm_v3<128, 128, 4><<<6288, 256, 0, stream>>>(xf_bf, embed_bf, vpad, nullptr,
        nullptr, NVOCAB, DMODEL, VPAD_LD, 1.0f);
    k_copy_out<<<MTOK, 256, 0, stream>>>(vpad, out);
  } else {
    k_gemm_v3<128, 128, 2><<<6288, 256, 0, stream>>>(xf_bf, embed_bf, out, nullptr,
        nullptr, NVOCAB, DMODEL, NVOCAB, 1.0f);
  }
}